// Round 6
// baseline (180.320 us; speedup 1.0000x reference)
//
#include <hip/hip_runtime.h>
#include <math.h>

#define NN 50000
#define NE 800000
#define D 64
#define NC 40
#define NBUCK 196   // ceil(NN/256) coarse buckets (bucket = dst >> 8)
#define SLAB 16384  // slots per bucket slab (avg fill ~4082; no overflow possible)
#define EPB 2048    // edges per scatter block (8/thread; 391 blocks)
#define PADROW 0xC350C350u  // two u16 pad indices = NN (zero row)

typedef unsigned short u16;
typedef unsigned int u32;

__device__ __forceinline__ u16 f32_to_bf16(float v) {
    u32 x = __float_as_uint(v);
    x += 0x7FFFu + ((x >> 16) & 1u);  // round-to-nearest-even
    return (u16)(x >> 16);
}
// packed u32 = two bf16: low u16 = dim 2k, high u16 = dim 2k+1
__device__ __forceinline__ float bflo(u32 v) { return __uint_as_float(v << 16); }
__device__ __forceinline__ float bfhi(u32 v) { return __uint_as_float(v & 0xffff0000u); }

// ---------------- phase 1: bin edges into coarse bucket slabs ----------------

__global__ __launch_bounds__(256) void bucket_scatter(const int* __restrict__ ei,
                                                      int* __restrict__ cursor,
                                                      u32* __restrict__ slab) {
    __shared__ int sums[256];
    __shared__ int lofs[256];
    __shared__ int lcur[256];
    __shared__ int gbase[256];
    __shared__ int tot_s;
    __shared__ u32 sorted[EPB];
    __shared__ int gdest[EPB];
    int tid = threadIdx.x;

    u32 pk[8];
    int nmine = 0;
    int e0 = blockIdx.x * EPB + tid * 8;
    if (e0 < NE) {
        nmine = 8;
#pragma unroll
        for (int j = 0; j < 2; ++j) {
            int4 ss = *(const int4*)&ei[e0 + j * 4];
            int4 dd = *(const int4*)&ei[NE + e0 + j * 4];
            pk[j * 4 + 0] = ((u32)dd.x << 16) | (u32)ss.x;
            pk[j * 4 + 1] = ((u32)dd.y << 16) | (u32)ss.y;
            pk[j * 4 + 2] = ((u32)dd.z << 16) | (u32)ss.z;
            pk[j * 4 + 3] = ((u32)dd.w << 16) | (u32)ss.w;
        }
    }

    sums[tid] = 0;
    __syncthreads();
    for (int j = 0; j < nmine; ++j) atomicAdd(&sums[pk[j] >> 24], 1);
    __syncthreads();
    int v = sums[tid];
    __syncthreads();
    for (int off = 1; off < 256; off <<= 1) {
        int u = (tid >= off) ? sums[tid - off] : 0;
        __syncthreads();
        sums[tid] += u;
        __syncthreads();
    }
    lofs[tid] = sums[tid] - v;
    lcur[tid] = sums[tid] - v;
    if (tid == 255) tot_s = sums[255];
    if (tid < NBUCK) gbase[tid] = atomicAdd(&cursor[tid], v);
    __syncthreads();

    for (int j = 0; j < nmine; ++j) {
        u32 p = pk[j];
        int bin = (int)(p >> 24);
        int pos = atomicAdd(&lcur[bin], 1);
        sorted[pos] = p;
        gdest[pos] = bin * SLAB + gbase[bin] + (pos - lofs[bin]);
    }
    __syncthreads();

    int tot = tot_s;
    for (int i = tid; i < tot; i += 256) slab[gdest[i]] = sorted[i];
}

// ---------------- phase 2: per-bucket ELL tile in LDS, coalesced write-out ----------------
// Pad slots hold index NN (a zeroed feature row) -> gather needs NO per-slot masking.

__global__ __launch_bounds__(256) void ell_build(const u32* __restrict__ slab,
                                                 const int* __restrict__ cursor,
                                                 u16* __restrict__ ell,
                                                 int* __restrict__ cnt,
                                                 float* __restrict__ dinv) {
    __shared__ u16 ell_lds[256 * 64];  // 32 KB
    __shared__ int cnt_lds[256];
    int b = blockIdx.x, tid = threadIdx.x;
    uint4* z = (uint4*)ell_lds;
    for (int i = tid; i < 2048; i += 256) z[i] = make_uint4(PADROW, PADROW, PADROW, PADROW);
    cnt_lds[tid] = 0;
    __syncthreads();

    int nE = cursor[b];
    const u32* run = slab + b * SLAB;
    int base = b * 256;
    for (int i = tid; i < nE; i += 256) {
        u32 p = run[i];
        int dl = (int)(p >> 16) - base;
        int r = atomicAdd(&cnt_lds[dl], 1);
        if (r < 64) ell_lds[dl * 64 + r] = (u16)(p & 0xffffu);
    }
    __syncthreads();

    int nNodes = NN - base; if (nNodes > 256) nNodes = 256;
    const uint4* s4 = (const uint4*)ell_lds;
    uint4* d4 = (uint4*)(ell + (size_t)base * 64);
    int n4 = nNodes * 8;
    for (int i = tid; i < n4; i += 256) d4[i] = s4[i];
    if (tid < nNodes) {
        int c = cnt_lds[tid];
        cnt[base + tid] = c;
        dinv[base + tid] = rsqrtf((float)c + 1.0f);
    }
}

// ---------------- layer-0 dense transform: 16 rows/block, split-half bf16 output ----------

__global__ __launch_bounds__(256) void gemm64_bf16(const float* __restrict__ A,
                                                   const float* __restrict__ W,
                                                   const float* __restrict__ dinv,
                                                   u16* __restrict__ Clo,
                                                   u16* __restrict__ Chi) {
    __shared__ float Ws[64 * 64];
    __shared__ __align__(16) float As[16 * 64];
    int tid = threadIdx.x;
    {   // stage W: 4096 floats = 4 float4/thread, coalesced
        const float4* w4 = (const float4*)W;
        float4* ws4 = (float4*)Ws;
#pragma unroll
        for (int j = 0; j < 4; ++j) ws4[tid + 256 * j] = w4[tid + 256 * j];
    }
    {   // stage 16 rows of A: 1024 floats = exactly 256 float4 (NN = 3125*16)
        const float4* a4 = (const float4*)(A + (size_t)blockIdx.x * 16 * 64);
        ((float4*)As)[tid] = a4[tid];
    }
    // zero pad row NN of both half outputs (gather pad target; 16 u32 = 64B each)
    if (blockIdx.x == 0 && tid < 16) ((u32*)(Clo + (size_t)NN * 32))[tid] = 0u;
    if (blockIdx.x == 0 && tid >= 16 && tid < 32) ((u32*)(Chi + (size_t)NN * 32))[tid - 16] = 0u;
    __syncthreads();

    int r = tid >> 6, c = tid & 63;   // wave-uniform r; rows r, r+4, r+8, r+12
    int rowBase = blockIdx.x * 16;
    float o0 = 0.f, o1 = 0.f, o2 = 0.f, o3 = 0.f;
#pragma unroll
    for (int k4 = 0; k4 < 16; ++k4) {
        float4 a0 = *(const float4*)&As[(r + 0) * 64 + k4 * 4];   // broadcast, free
        float4 a1 = *(const float4*)&As[(r + 4) * 64 + k4 * 4];
        float4 a2 = *(const float4*)&As[(r + 8) * 64 + k4 * 4];
        float4 a3 = *(const float4*)&As[(r + 12) * 64 + k4 * 4];
        float w0 = Ws[(k4 * 4 + 0) * 64 + c];
        float w1 = Ws[(k4 * 4 + 1) * 64 + c];
        float w2 = Ws[(k4 * 4 + 2) * 64 + c];
        float w3 = Ws[(k4 * 4 + 3) * 64 + c];
        o0 += a0.x * w0 + a0.y * w1 + a0.z * w2 + a0.w * w3;
        o1 += a1.x * w0 + a1.y * w1 + a1.z * w2 + a1.w * w3;
        o2 += a2.x * w0 + a2.y * w1 + a2.z * w2 + a2.w * w3;
        o3 += a3.x * w0 + a3.y * w1 + a3.z * w2 + a3.w * w3;
    }
    u16* Ch = (c < 32) ? Clo : Chi;
    int cc = c & 31;
    Ch[(size_t)(rowBase + r +  0) * 32 + cc] = f32_to_bf16(o0 * dinv[rowBase + r +  0]);
    Ch[(size_t)(rowBase + r +  4) * 32 + cc] = f32_to_bf16(o1 * dinv[rowBase + r +  4]);
    Ch[(size_t)(rowBase + r +  8) * 32 + cc] = f32_to_bf16(o2 * dinv[rowBase + r +  8]);
    Ch[(size_t)(rowBase + r + 12) * 32 + cc] = f32_to_bf16(o3 * dinv[rowBase + r + 12]);
}

// ---------------- gather core: HALF rows (32 dims), L2-resident working set -----------
// Lane l = q*16+p: quarter q owns node base+q; lane p holds dims [2p,2p+1] (one u32).
// Index structure identical to full-row version (iv = uint2 -> slots 4p..4p+3).
// Pad slots point at row NN (zeroed) -> unconditional accumulate. hsh = 3.2 MB.

__device__ __forceinline__ void gather_half(const u16* __restrict__ ell,
                                            const int* __restrict__ cnt,
                                            const u32* __restrict__ hsh,
                                            int base, int l,
                                            float& a0, float& a1) {
    int q = l >> 4, p = l & 15;
    int node = base + q;
    int4 c4 = *(const int4*)&cnt[base];
    int m01 = (c4.x > c4.y) ? c4.x : c4.y;
    int m23 = (c4.z > c4.w) ? c4.z : c4.w;
    int degmax = (m01 > m23) ? m01 : m23;  // wave-uniform
    if (degmax > 64) degmax = 64;

    uint2 iv = ((const uint2*)(ell + (size_t)node * 64))[p];  // slots 4p..4p+3

    u32 sv = hsh[node * 16 + p];  // self-loop row (cached, hot)
    a0 = bflo(sv); a1 = bfhi(sv);
    float e0 = 0.0f, e1 = 0.0f;

    for (int m = 0; m < degmax; m += 16) {
        u32 st[16];
#pragma unroll
        for (int u = 0; u < 16; ++u) {
            u32 wsel = ((u >> 1) & 1) ? iv.y : iv.x;            // compile-time select
            int bc = __shfl((int)wsel, (l & 48) + (m >> 2) + (u >> 2));
            int sid = (u & 1) ? (int)((u32)bc >> 16) : (int)(bc & 0xffff);
            st[u] = hsh[sid * 16 + p];                          // 16 independent dword loads
        }
#pragma unroll
        for (int u = 0; u < 16; ++u) {
            if (u & 1) { e0 += bflo(st[u]); e1 += bfhi(st[u]); }
            else       { a0 += bflo(st[u]); a1 += bfhi(st[u]); }
        }
    }
    a0 += e0; a1 += e1;
}

// ---------------- layer 1, pass A: gather lo dims -> tanh -> h1_lo (f32 stream) --------

__global__ __launch_bounds__(256) void gather_l1_lo(const u16* __restrict__ ell,
                                                    const int* __restrict__ cnt,
                                                    const u32* __restrict__ hs_lo,
                                                    const float* __restrict__ dinv,
                                                    const float* __restrict__ b1,
                                                    float* __restrict__ h1_lo) {
    int tid = threadIdx.x;
    int r = tid >> 6, l = tid & 63, q = l >> 4, p = l & 15;
    int base = (blockIdx.x * 4 + r) * 4;
    int node = base + q;

    float a0, a1;
    gather_half(ell, cnt, hs_lo, base, l, a0, a1);

    float dv = dinv[node];
    float2 bb = *(const float2*)&b1[p * 2];
    float2 h = make_float2(tanhf(a0 * dv + bb.x), tanhf(a1 * dv + bb.y));
    *(float2*)&h1_lo[(size_t)node * 32 + p * 2] = h;
}

// ---------------- layer 1, pass B: gather hi dims + h1_lo stream -> GEMM -> hsB --------

__global__ __launch_bounds__(256) void gather_l1_hi(const u16* __restrict__ ell,
                                                    const int* __restrict__ cnt,
                                                    const u32* __restrict__ hs_hi,
                                                    const float* __restrict__ h1_lo,
                                                    const float* __restrict__ dinv,
                                                    const float* __restrict__ b1,
                                                    const float* __restrict__ W2,
                                                    u16* __restrict__ hsB_lo,
                                                    u16* __restrict__ hsB_hi) {
    __shared__ float Ws[64 * 64];
    __shared__ __align__(16) float hb[4][4][64];
    int tid = threadIdx.x;
    {   // stage W2 (no barrier yet; completes under the gather)
        const float4* w4 = (const float4*)W2;
        float4* ws4 = (float4*)Ws;
#pragma unroll
        for (int j = 0; j < 4; ++j) ws4[tid + 256 * j] = w4[tid + 256 * j];
    }
    // zero pad row NN of both hsB halves (gather_l2 pad target)
    if (blockIdx.x == 0 && tid < 16) ((u32*)(hsB_lo + (size_t)NN * 32))[tid] = 0u;
    if (blockIdx.x == 0 && tid >= 16 && tid < 32) ((u32*)(hsB_hi + (size_t)NN * 32))[tid - 16] = 0u;

    int r = tid >> 6, l = tid & 63, q = l >> 4, p = l & 15;
    int base = (blockIdx.x * 4 + r) * 4;
    int node = base + q;

    float a0, a1;
    gather_half(ell, cnt, hs_hi, base, l, a0, a1);

    float dv = dinv[node];
    float2 bb = *(const float2*)&b1[32 + p * 2];
    float2 h = make_float2(tanhf(a0 * dv + bb.x), tanhf(a1 * dv + bb.y));
    *(float2*)&hb[r][q][32 + p * 2] = h;
    {   // pull the lo half (written by pass A) into the wave's LDS row block
        float2 lo = *(const float2*)&h1_lo[(size_t)node * 32 + p * 2];
        *(float2*)&hb[r][q][p * 2] = lo;
    }
    __syncthreads();  // Ws staging + hb complete

    int d = l;
    float4 dvv = *(const float4*)&dinv[base];
    float o0 = 0.0f, o1 = 0.0f, o2 = 0.0f, o3 = 0.0f;
#pragma unroll
    for (int k4 = 0; k4 < 16; ++k4) {
        float4 h0 = *(const float4*)&hb[r][0][k4 * 4];
        float4 h1 = *(const float4*)&hb[r][1][k4 * 4];
        float4 h2 = *(const float4*)&hb[r][2][k4 * 4];
        float4 h3 = *(const float4*)&hb[r][3][k4 * 4];
        float w0 = Ws[(k4 * 4 + 0) * 64 + d];
        float w1 = Ws[(k4 * 4 + 1) * 64 + d];
        float w2 = Ws[(k4 * 4 + 2) * 64 + d];
        float w3 = Ws[(k4 * 4 + 3) * 64 + d];
        o0 += h0.x * w0 + h0.y * w1 + h0.z * w2 + h0.w * w3;
        o1 += h1.x * w0 + h1.y * w1 + h1.z * w2 + h1.w * w3;
        o2 += h2.x * w0 + h2.y * w1 + h2.z * w2 + h2.w * w3;
        o3 += h3.x * w0 + h3.y * w1 + h3.z * w2 + h3.w * w3;
    }
    u16* Bh = (d < 32) ? hsB_lo : hsB_hi;
    int dd = d & 31;
    __builtin_nontemporal_store(f32_to_bf16(o0 * dvv.x), &Bh[(size_t)(base + 0) * 32 + dd]);
    __builtin_nontemporal_store(f32_to_bf16(o1 * dvv.y), &Bh[(size_t)(base + 1) * 32 + dd]);
    __builtin_nontemporal_store(f32_to_bf16(o2 * dvv.z), &Bh[(size_t)(base + 2) * 32 + dd]);
    __builtin_nontemporal_store(f32_to_bf16(o3 * dvv.w), &Bh[(size_t)(base + 3) * 32 + dd]);
}

// ---------------- layer 2, pass A: gather lo dims -> tanh -> h_out dims 0..31 ----------

__global__ __launch_bounds__(256) void gather_l2_lo(const u16* __restrict__ ell,
                                                    const int* __restrict__ cnt,
                                                    const u32* __restrict__ hsB_lo,
                                                    const float* __restrict__ dinv,
                                                    const float* __restrict__ b2,
                                                    float* __restrict__ h_out) {
    int tid = threadIdx.x;
    int r = tid >> 6, l = tid & 63, q = l >> 4, p = l & 15;
    int base = (blockIdx.x * 4 + r) * 4;
    int node = base + q;

    float a0, a1;
    gather_half(ell, cnt, hsB_lo, base, l, a0, a1);

    float dv = dinv[node];
    float2 bb = *(const float2*)&b2[p * 2];
    float2 h = make_float2(tanhf(a0 * dv + bb.x), tanhf(a1 * dv + bb.y));
    *(float2*)&h_out[(size_t)node * 64 + p * 2] = h;
}

// ---------------- layer 2, pass B: gather hi dims + h_out lo -> classifier -------------

__global__ __launch_bounds__(256) void gather_l2_hi(const u16* __restrict__ ell,
                                                    const int* __restrict__ cnt,
                                                    const u32* __restrict__ hsB_hi,
                                                    const float* __restrict__ dinv,
                                                    const float* __restrict__ b2,
                                                    const float* __restrict__ Wc,
                                                    const float* __restrict__ bc,
                                                    float* __restrict__ h_out,
                                                    float* __restrict__ out) {
    __shared__ float Ws[64 * NC];
    __shared__ float bs[NC];
    __shared__ __align__(16) float hb[4][4][64];
    int tid = threadIdx.x;
    for (int i = tid; i < 64 * NC; i += 256) Ws[i] = Wc[i];  // issued, no barrier yet
    if (tid < NC) bs[tid] = bc[tid];

    int r = tid >> 6, l = tid & 63, q = l >> 4, p = l & 15;
    int base = (blockIdx.x * 4 + r) * 4;
    int node = base + q;

    float a0, a1;
    gather_half(ell, cnt, hsB_hi, base, l, a0, a1);

    float dv = dinv[node];
    float2 bb = *(const float2*)&b2[32 + p * 2];
    float2 h = make_float2(tanhf(a0 * dv + bb.x), tanhf(a1 * dv + bb.y));
    *(float2*)&h_out[(size_t)node * 64 + 32 + p * 2] = h;
    *(float2*)&hb[r][q][32 + p * 2] = h;
    {   // pull lo half (written by pass A into the output buffer)
        float2 lo = *(const float2*)&h_out[(size_t)node * 64 + p * 2];
        *(float2*)&hb[r][q][p * 2] = lo;
    }
    __syncthreads();  // Ws/bs staging + hb complete

    int d = l;
    int dc = (d < NC) ? d : NC - 1;
    float bcd = bs[dc];
    float o0 = bcd, o1 = bcd, o2 = bcd, o3 = bcd;
#pragma unroll
    for (int k4 = 0; k4 < 16; ++k4) {
        float4 v0 = *(const float4*)&hb[r][0][k4 * 4];
        float4 v1 = *(const float4*)&hb[r][1][k4 * 4];
        float4 v2 = *(const float4*)&hb[r][2][k4 * 4];
        float4 v3 = *(const float4*)&hb[r][3][k4 * 4];
        float w0 = Ws[(k4 * 4 + 0) * NC + dc];
        float w1 = Ws[(k4 * 4 + 1) * NC + dc];
        float w2 = Ws[(k4 * 4 + 2) * NC + dc];
        float w3 = Ws[(k4 * 4 + 3) * NC + dc];
        o0 += v0.x * w0 + v0.y * w1 + v0.z * w2 + v0.w * w3;
        o1 += v1.x * w0 + v1.y * w1 + v1.z * w2 + v1.w * w3;
        o2 += v2.x * w0 + v2.y * w1 + v2.z * w2 + v2.w * w3;
        o3 += v3.x * w0 + v3.y * w1 + v3.z * w2 + v3.w * w3;
    }
    if (d < NC) {
        __builtin_nontemporal_store(o0, &out[(size_t)(base + 0) * NC + d]);
        __builtin_nontemporal_store(o1, &out[(size_t)(base + 1) * NC + d]);
        __builtin_nontemporal_store(o2, &out[(size_t)(base + 2) * NC + d]);
        __builtin_nontemporal_store(o3, &out[(size_t)(base + 3) * NC + d]);
    }
}

// ---------------- launch ----------------

extern "C" void kernel_launch(void* const* d_in, const int* in_sizes, int n_in,
                              void* d_out, int out_size, void* d_ws, size_t ws_size,
                              hipStream_t stream) {
    const float* x  = (const float*)d_in[0];
    const int*   ei = (const int*)d_in[1];
    const float* W1 = (const float*)d_in[2];
    const float* b1 = (const float*)d_in[3];
    const float* W2 = (const float*)d_in[4];
    const float* b2 = (const float*)d_in[5];
    const float* Wc = (const float*)d_in[6];
    const float* bc = (const float*)d_in[7];

    float* out   = (float*)d_out;   // [NN, 40]
    float* h_out = out + NN * NC;   // [NN, 64]

    // workspace (64B-aligned segments); half-feature arrays have NN+1 rows (row NN = 0)
    u32*   slab    = (u32*)d_ws;                        // NBUCK*SLAB u32 = 12.8 MB
    int*   cursor  = (int*)(slab + NBUCK * SLAB);       // 256 i32
    int*   cnt     = cursor + 256;                      // NN i32
    float* dinv    = (float*)(cnt + NN);                // NN f32
    u16*   ell     = (u16*)(dinv + NN);                 // NN*64 u16 = 6.4 MB
    u16*   hsA_lo  = ell + (size_t)NN * 64;             // (NN+1)*32 u16 = 3.2 MB
    u16*   hsA_hi  = hsA_lo + (size_t)(NN + 1) * 32;    // (NN+1)*32 u16
    u16*   hsB_lo  = hsA_hi + (size_t)(NN + 1) * 32;    // (NN+1)*32 u16
    u16*   hsB_hi  = hsB_lo + (size_t)(NN + 1) * 32;    // (NN+1)*32 u16
    float* h1_lo   = (float*)(hsB_hi + (size_t)(NN + 1) * 32);  // NN*32 f32 = 6.4 MB

    const int scatBlocks   = (NE + EPB - 1) / EPB;      // 391
    const int nodeBlocks16 = NN / 16;                   // 3125

    // two-phase binned ELL build
    hipMemsetAsync(cursor, 0, NBUCK * sizeof(int), stream);
    bucket_scatter<<<scatBlocks, 256, 0, stream>>>(ei, cursor, slab);
    ell_build<<<NBUCK, 256, 0, stream>>>(slab, cursor, ell, cnt, dinv);

    // layer 0 transform -> split halves
    gemm64_bf16<<<nodeBlocks16, 256, 0, stream>>>(x, W1, dinv, hsA_lo, hsA_hi);

    // layer 1: lo gather (3.2MB L2-resident) then hi gather + fused GEMM
    gather_l1_lo<<<nodeBlocks16, 256, 0, stream>>>(ell, cnt, (const u32*)hsA_lo, dinv, b1, h1_lo);
    gather_l1_hi<<<nodeBlocks16, 256, 0, stream>>>(ell, cnt, (const u32*)hsA_hi, h1_lo, dinv,
                                                   b1, W2, hsB_lo, hsB_hi);

    // layer 2: lo gather -> h_out lo dims; hi gather + classifier epilogue
    gather_l2_lo<<<nodeBlocks16, 256, 0, stream>>>(ell, cnt, (const u32*)hsB_lo, dinv, b2, h_out);
    gather_l2_hi<<<nodeBlocks16, 256, 0, stream>>>(ell, cnt, (const u32*)hsB_hi, dinv, b2,
                                                   Wc, bc, h_out, out);
}

// Round 7
// 169.043 us; speedup vs baseline: 1.0667x; 1.0667x over previous
//
#include <hip/hip_runtime.h>
#include <math.h>

#define NN 50000
#define NE 800000
#define D 64
#define NC 40
#define NBUCK 196   // ceil(NN/256) coarse buckets (bucket = dst >> 8)
#define SLAB 16384  // slots per bucket slab (avg fill ~4082; no overflow possible)
#define EPB 2048    // edges per scatter block (8/thread; 391 blocks)
#define PADROW 0xC350C350u  // two u16 pad indices = NN (zero row)

typedef unsigned short u16;
typedef unsigned int u32;

__device__ __forceinline__ u16 f32_to_bf16(float v) {
    u32 x = __float_as_uint(v);
    x += 0x7FFFu + ((x >> 16) & 1u);  // round-to-nearest-even
    return (u16)(x >> 16);
}
// packed u32 = two bf16: low u16 = dim 2k, high u16 = dim 2k+1
__device__ __forceinline__ float bflo(u32 v) { return __uint_as_float(v << 16); }
__device__ __forceinline__ float bfhi(u32 v) { return __uint_as_float(v & 0xffff0000u); }

// ---------------- phase 1: bin edges into coarse bucket slabs ----------------

__global__ __launch_bounds__(256) void bucket_scatter(const int* __restrict__ ei,
                                                      int* __restrict__ cursor,
                                                      u32* __restrict__ slab) {
    __shared__ int sums[256];
    __shared__ int lofs[256];
    __shared__ int lcur[256];
    __shared__ int gbase[256];
    __shared__ int tot_s;
    __shared__ u32 sorted[EPB];
    __shared__ int gdest[EPB];
    int tid = threadIdx.x;

    u32 pk[8];
    int nmine = 0;
    int e0 = blockIdx.x * EPB + tid * 8;
    if (e0 < NE) {
        nmine = 8;
#pragma unroll
        for (int j = 0; j < 2; ++j) {
            int4 ss = *(const int4*)&ei[e0 + j * 4];
            int4 dd = *(const int4*)&ei[NE + e0 + j * 4];
            pk[j * 4 + 0] = ((u32)dd.x << 16) | (u32)ss.x;
            pk[j * 4 + 1] = ((u32)dd.y << 16) | (u32)ss.y;
            pk[j * 4 + 2] = ((u32)dd.z << 16) | (u32)ss.z;
            pk[j * 4 + 3] = ((u32)dd.w << 16) | (u32)ss.w;
        }
    }

    sums[tid] = 0;
    __syncthreads();
    for (int j = 0; j < nmine; ++j) atomicAdd(&sums[pk[j] >> 24], 1);
    __syncthreads();
    int v = sums[tid];
    __syncthreads();
    for (int off = 1; off < 256; off <<= 1) {
        int u = (tid >= off) ? sums[tid - off] : 0;
        __syncthreads();
        sums[tid] += u;
        __syncthreads();
    }
    lofs[tid] = sums[tid] - v;
    lcur[tid] = sums[tid] - v;
    if (tid == 255) tot_s = sums[255];
    if (tid < NBUCK) gbase[tid] = atomicAdd(&cursor[tid], v);
    __syncthreads();

    for (int j = 0; j < nmine; ++j) {
        u32 p = pk[j];
        int bin = (int)(p >> 24);
        int pos = atomicAdd(&lcur[bin], 1);
        sorted[pos] = p;
        gdest[pos] = bin * SLAB + gbase[bin] + (pos - lofs[bin]);
    }
    __syncthreads();

    int tot = tot_s;
    for (int i = tid; i < tot; i += 256) slab[gdest[i]] = sorted[i];
}

// ---------------- phase 2: per-quarter-bucket ELL tile in LDS ----------------
// 4 sub-blocks per bucket (grid 784 vs 196): each scans the bucket run and keeps
// only its 64-node quarter -> 4x CU coverage, 4x fewer serial LDS atomics/block.
// Pad slots hold index NN (a zeroed feature row) -> gather needs NO masking.

__global__ __launch_bounds__(256) void ell_build(const u32* __restrict__ slab,
                                                 const int* __restrict__ cursor,
                                                 u16* __restrict__ ell,
                                                 int* __restrict__ cnt,
                                                 float* __restrict__ dinv) {
    __shared__ u16 ell_lds[64 * 64];  // 8 KB
    __shared__ int cnt_lds[64];
    int b = blockIdx.x >> 2, sub = blockIdx.x & 3, tid = threadIdx.x;
    int base = b * 256 + sub * 64;
    int nNodes = NN - base;
    if (nNodes <= 0) return;          // bucket 195 sub2/3: no nodes
    if (nNodes > 64) nNodes = 64;

    uint4* z = (uint4*)ell_lds;
#pragma unroll
    for (int j = 0; j < 2; ++j) z[tid + 256 * j] = make_uint4(PADROW, PADROW, PADROW, PADROW);
    if (tid < 64) cnt_lds[tid] = 0;
    __syncthreads();

    int nE = cursor[b];
    const u32* run = slab + b * SLAB;
    for (int i = tid; i < nE; i += 256) {
        u32 p = run[i];
        int dl = (int)(p >> 16) - base;
        if ((u32)dl < 64u) {
            int r = atomicAdd(&cnt_lds[dl], 1);
            if (r < 64) ell_lds[dl * 64 + r] = (u16)(p & 0xffffu);
        }
    }
    __syncthreads();

    const uint4* s4 = (const uint4*)ell_lds;
    uint4* d4 = (uint4*)(ell + (size_t)base * 64);
    int n4 = nNodes * 8;
    for (int i = tid; i < n4; i += 256) d4[i] = s4[i];
    if (tid < nNodes) {
        int c = cnt_lds[tid];
        cnt[base + tid] = c;
        dinv[base + tid] = rsqrtf((float)c + 1.0f);
    }
}

// ---------------- layer-0 dense transform: 16 rows/block, W staged once ----------------

__global__ __launch_bounds__(256) void gemm64_bf16(const float* __restrict__ A,
                                                   const float* __restrict__ W,
                                                   const float* __restrict__ dinv,
                                                   u16* __restrict__ C) {
    __shared__ float Ws[64 * 64];
    __shared__ __align__(16) float As[16 * 64];
    int tid = threadIdx.x;
    {   // stage W: 4096 floats = 4 float4/thread, coalesced
        const float4* w4 = (const float4*)W;
        float4* ws4 = (float4*)Ws;
#pragma unroll
        for (int j = 0; j < 4; ++j) ws4[tid + 256 * j] = w4[tid + 256 * j];
    }
    {   // stage 16 rows of A: 1024 floats = exactly 256 float4 (NN = 3125*16)
        const float4* a4 = (const float4*)(A + (size_t)blockIdx.x * 16 * 64);
        ((float4*)As)[tid] = a4[tid];
    }
    // zero pad row NN of the bf16 output (gather pad target)
    if (blockIdx.x == 0 && tid < 32) ((u32*)(C + (size_t)NN * 64))[tid] = 0u;
    __syncthreads();

    int r = tid >> 6, c = tid & 63;   // wave-uniform r; rows r, r+4, r+8, r+12
    int rowBase = blockIdx.x * 16;
    float o0 = 0.f, o1 = 0.f, o2 = 0.f, o3 = 0.f;
#pragma unroll
    for (int k4 = 0; k4 < 16; ++k4) {
        float4 a0 = *(const float4*)&As[(r + 0) * 64 + k4 * 4];   // broadcast, free
        float4 a1 = *(const float4*)&As[(r + 4) * 64 + k4 * 4];
        float4 a2 = *(const float4*)&As[(r + 8) * 64 + k4 * 4];
        float4 a3 = *(const float4*)&As[(r + 12) * 64 + k4 * 4];
        float w0 = Ws[(k4 * 4 + 0) * 64 + c];                     // stride-1, conflict-free
        float w1 = Ws[(k4 * 4 + 1) * 64 + c];
        float w2 = Ws[(k4 * 4 + 2) * 64 + c];
        float w3 = Ws[(k4 * 4 + 3) * 64 + c];
        o0 += a0.x * w0 + a0.y * w1 + a0.z * w2 + a0.w * w3;
        o1 += a1.x * w0 + a1.y * w1 + a1.z * w2 + a1.w * w3;
        o2 += a2.x * w0 + a2.y * w1 + a2.z * w2 + a2.w * w3;
        o3 += a3.x * w0 + a3.y * w1 + a3.z * w2 + a3.w * w3;
    }
    C[(size_t)(rowBase + r +  0) * 64 + c] = f32_to_bf16(o0 * dinv[rowBase + r +  0]);
    C[(size_t)(rowBase + r +  4) * 64 + c] = f32_to_bf16(o1 * dinv[rowBase + r +  4]);
    C[(size_t)(rowBase + r +  8) * 64 + c] = f32_to_bf16(o2 * dinv[rowBase + r +  8]);
    C[(size_t)(rowBase + r + 12) * 64 + c] = f32_to_bf16(o3 * dinv[rowBase + r + 12]);
}

// ---------------- gather core: quarter-wave, 4 nodes/wave, 16-deep batches ----------------

// Lane l = q*16+p: quarter q owns node base+q; lane p holds dims [4p..4p+3] (uint2).
// Index row (64 u16 slots) lives in ONE uint2 per lane; per-edge broadcast via
// __shfl with compile-time word/half selects. 16 independent loads per batch.
// NO per-slot masking: pad slots point at row NN (zeroed) -> accumulate +0.0f.
__device__ __forceinline__ void gather_quad(const u16* __restrict__ ell,
                                            const int* __restrict__ cnt,
                                            const uint2* __restrict__ hs2,
                                            int base, int l,
                                            float& a0, float& a1, float& a2, float& a3) {
    int q = l >> 4, p = l & 15;
    int node = base + q;
    int4 c4 = *(const int4*)&cnt[base];
    int m01 = (c4.x > c4.y) ? c4.x : c4.y;
    int m23 = (c4.z > c4.w) ? c4.z : c4.w;
    int degmax = (m01 > m23) ? m01 : m23;  // wave-uniform
    if (degmax > 64) degmax = 64;

    uint2 iv = ((const uint2*)(ell + (size_t)node * 64))[p];  // slots 4p..4p+3

    uint2 sv = hs2[node * 16 + p];  // self-loop row
    a0 = bflo(sv.x); a1 = bfhi(sv.x); a2 = bflo(sv.y); a3 = bfhi(sv.y);
    float e0 = 0.0f, e1 = 0.0f, e2 = 0.0f, e3 = 0.0f;

    for (int m = 0; m < degmax; m += 16) {
        uint2 st[16];
#pragma unroll
        for (int u = 0; u < 16; ++u) {
            u32 wsel = ((u >> 1) & 1) ? iv.y : iv.x;            // compile-time select
            int bc = __shfl((int)wsel, (l & 48) + (m >> 2) + (u >> 2));
            int sid = (u & 1) ? (int)((u32)bc >> 16) : (int)(bc & 0xffff);
            st[u] = hs2[sid * 16 + p];                          // 16 independent loads
        }
#pragma unroll
        for (int u = 0; u < 16; ++u) {
            u32 x = st[u].x, y = st[u].y;
            if (u & 1) { e0 += bflo(x); e1 += bfhi(x); e2 += bflo(y); e3 += bfhi(y); }
            else       { a0 += bflo(x); a1 += bfhi(x); a2 += bflo(y); a3 += bfhi(y); }
        }
    }
    a0 += e0; a1 += e1; a2 += e2; a3 += e3;
}

// ---------------- fused gather kernels ----------------

// Layer 1: gather+tanh (4 nodes/wave) -> per-wave LDS stage -> h1 @ W2 * dinv -> bf16.
// Ws staging loads issued BEFORE the gather; barrier deferred to after the gather.
__global__ __launch_bounds__(256) void gather_l1_fused(const u16* __restrict__ ell,
                                                       const int* __restrict__ cnt,
                                                       const u16* __restrict__ hs,
                                                       const float* __restrict__ dinv,
                                                       const float* __restrict__ b1,
                                                       const float* __restrict__ W2,
                                                       u16* __restrict__ hs_out) {
    __shared__ float Ws[64 * 64];
    __shared__ __align__(16) float hb[4][4][64];
    int tid = threadIdx.x;
    {   // stage W2: 4096 floats = 4 float4/thread, coalesced (no barrier yet)
        const float4* w4 = (const float4*)W2;
        float4* ws4 = (float4*)Ws;
#pragma unroll
        for (int j = 0; j < 4; ++j) ws4[tid + 256 * j] = w4[tid + 256 * j];
    }
    // zero pad row NN of the bf16 output (gather_l2 pad target)
    if (blockIdx.x == 0 && tid < 32) ((u32*)(hs_out + (size_t)NN * 64))[tid] = 0u;

    int r = tid >> 6, l = tid & 63, q = l >> 4, p = l & 15;
    int base = (blockIdx.x * 4 + r) * 4;  // NN divisible by 16
    int node = base + q;

    float a0, a1, a2, a3;
    gather_quad(ell, cnt, (const uint2*)hs, base, l, a0, a1, a2, a3);

    float dv = dinv[node];
    float4 bb = *(const float4*)&b1[p * 4];
    float4 h = make_float4(tanhf(a0 * dv + bb.x), tanhf(a1 * dv + bb.y),
                           tanhf(a2 * dv + bb.z), tanhf(a3 * dv + bb.w));
    *(float4*)&hb[r][q][p * 4] = h;
    __syncthreads();  // Ws staging complete (hidden under gather) + hb visibility

    int d = l;
    float4 dvv = *(const float4*)&dinv[base];
    float o0 = 0.0f, o1 = 0.0f, o2 = 0.0f, o3 = 0.0f;
#pragma unroll
    for (int k4 = 0; k4 < 16; ++k4) {
        float4 h0 = *(const float4*)&hb[r][0][k4 * 4];
        float4 h1 = *(const float4*)&hb[r][1][k4 * 4];
        float4 h2 = *(const float4*)&hb[r][2][k4 * 4];
        float4 h3 = *(const float4*)&hb[r][3][k4 * 4];
        float w0 = Ws[(k4 * 4 + 0) * 64 + d];
        float w1 = Ws[(k4 * 4 + 1) * 64 + d];
        float w2 = Ws[(k4 * 4 + 2) * 64 + d];
        float w3 = Ws[(k4 * 4 + 3) * 64 + d];
        o0 += h0.x * w0 + h0.y * w1 + h0.z * w2 + h0.w * w3;
        o1 += h1.x * w0 + h1.y * w1 + h1.z * w2 + h1.w * w3;
        o2 += h2.x * w0 + h2.y * w1 + h2.z * w2 + h2.w * w3;
        o3 += h3.x * w0 + h3.y * w1 + h3.z * w2 + h3.w * w3;
    }
    hs_out[(base + 0) * 64 + d] = f32_to_bf16(o0 * dvv.x);
    hs_out[(base + 1) * 64 + d] = f32_to_bf16(o1 * dvv.y);
    hs_out[(base + 2) * 64 + d] = f32_to_bf16(o2 * dvv.z);
    hs_out[(base + 3) * 64 + d] = f32_to_bf16(o3 * dvv.w);
}

// Layer 2: gather+tanh -> h_out (f32, float4 coalesced) -> classifier epilogue.
__global__ __launch_bounds__(256) void gather_l2_fused(const u16* __restrict__ ell,
                                                       const int* __restrict__ cnt,
                                                       const u16* __restrict__ hs,
                                                       const float* __restrict__ dinv,
                                                       const float* __restrict__ b2,
                                                       const float* __restrict__ Wc,
                                                       const float* __restrict__ bc,
                                                       float* __restrict__ h_out,
                                                       float* __restrict__ out) {
    __shared__ float Ws[64 * NC];
    __shared__ float bs[NC];
    __shared__ __align__(16) float hb[4][4][64];
    int tid = threadIdx.x;
    for (int i = tid; i < 64 * NC; i += 256) Ws[i] = Wc[i];  // issued, no barrier yet
    if (tid < NC) bs[tid] = bc[tid];

    int r = tid >> 6, l = tid & 63, q = l >> 4, p = l & 15;
    int base = (blockIdx.x * 4 + r) * 4;
    int node = base + q;

    float a0, a1, a2, a3;
    gather_quad(ell, cnt, (const uint2*)hs, base, l, a0, a1, a2, a3);

    float dv = dinv[node];
    float4 bb = *(const float4*)&b2[p * 4];
    float4 h = make_float4(tanhf(a0 * dv + bb.x), tanhf(a1 * dv + bb.y),
                           tanhf(a2 * dv + bb.z), tanhf(a3 * dv + bb.w));
    *(float4*)&h_out[node * 64 + p * 4] = h;  // 16 lanes x 16B = full row, coalesced
    *(float4*)&hb[r][q][p * 4] = h;
    __syncthreads();  // Ws/bs staging complete (hidden under gather) + hb visibility

    int d = l;
    int dc = (d < NC) ? d : NC - 1;
    float bcd = bs[dc];
    float o0 = bcd, o1 = bcd, o2 = bcd, o3 = bcd;
#pragma unroll
    for (int k4 = 0; k4 < 16; ++k4) {
        float4 v0 = *(const float4*)&hb[r][0][k4 * 4];
        float4 v1 = *(const float4*)&hb[r][1][k4 * 4];
        float4 v2 = *(const float4*)&hb[r][2][k4 * 4];
        float4 v3 = *(const float4*)&hb[r][3][k4 * 4];
        float w0 = Ws[(k4 * 4 + 0) * NC + dc];
        float w1 = Ws[(k4 * 4 + 1) * NC + dc];
        float w2 = Ws[(k4 * 4 + 2) * NC + dc];
        float w3 = Ws[(k4 * 4 + 3) * NC + dc];
        o0 += v0.x * w0 + v0.y * w1 + v0.z * w2 + v0.w * w3;
        o1 += v1.x * w0 + v1.y * w1 + v1.z * w2 + v1.w * w3;
        o2 += v2.x * w0 + v2.y * w1 + v2.z * w2 + v2.w * w3;
        o3 += v3.x * w0 + v3.y * w1 + v3.z * w2 + v3.w * w3;
    }
    if (d < NC) {
        out[(base + 0) * NC + d] = o0;
        out[(base + 1) * NC + d] = o1;
        out[(base + 2) * NC + d] = o2;
        out[(base + 3) * NC + d] = o3;
    }
}

// ---------------- launch ----------------

extern "C" void kernel_launch(void* const* d_in, const int* in_sizes, int n_in,
                              void* d_out, int out_size, void* d_ws, size_t ws_size,
                              hipStream_t stream) {
    const float* x  = (const float*)d_in[0];
    const int*   ei = (const int*)d_in[1];
    const float* W1 = (const float*)d_in[2];
    const float* b1 = (const float*)d_in[3];
    const float* W2 = (const float*)d_in[4];
    const float* b2 = (const float*)d_in[5];
    const float* Wc = (const float*)d_in[6];
    const float* bc = (const float*)d_in[7];

    float* out   = (float*)d_out;   // [NN, 40]
    float* h_out = out + NN * NC;   // [NN, 64]

    // workspace (16B-aligned segments); hsA/hsB have NN+1 rows (row NN = zero pad)
    u32*   slab   = (u32*)d_ws;                       // NBUCK*SLAB u32 = 12.8 MB
    int*   cursor = (int*)(slab + NBUCK * SLAB);      // NBUCK (+pad to 256)
    int*   cnt    = cursor + 256;                     // NN i32
    float* dinv   = (float*)(cnt + NN);               // NN f32
    u16*   ell    = (u16*)(dinv + NN);                // NN*64 u16 = 6.4 MB
    u16*   hsA    = ell + (size_t)NN * 64;            // (NN+1)*64 u16
    u16*   hsB    = hsA + (size_t)(NN + 1) * 64;      // (NN+1)*64 u16

    const int scatBlocks   = (NE + EPB - 1) / EPB;    // 391
    const int nodeBlocks16 = NN / 16;                 // 3125 (NN divisible by 16)

    // two-phase binned ELL build (ell_build: 4 sub-blocks per bucket)
    hipMemsetAsync(cursor, 0, NBUCK * sizeof(int), stream);
    bucket_scatter<<<scatBlocks, 256, 0, stream>>>(ei, cursor, slab);
    ell_build<<<NBUCK * 4, 256, 0, stream>>>(slab, cursor, ell, cnt, dinv);

    // layer 0 transform (16 rows/block), then fused layer 1 and layer 2
    gemm64_bf16<<<nodeBlocks16, 256, 0, stream>>>(x, W1, dinv, hsA);
    gather_l1_fused<<<nodeBlocks16, 256, 0, stream>>>(ell, cnt, hsA, dinv, b1, W2, hsB);
    gather_l2_fused<<<nodeBlocks16, 256, 0, stream>>>(ell, cnt, hsB, dinv, b2, Wc, bc,
                                                      h_out, out);
}